// Round 1
// baseline (1324.140 us; speedup 1.0000x reference)
//
#include <hip/hip_runtime.h>

typedef __bf16 bf16;
typedef __bf16 bf16x8 __attribute__((ext_vector_type(8)));
typedef __bf16 bf16x4 __attribute__((ext_vector_type(4)));
typedef float f32x4 __attribute__((ext_vector_type(4)));

#define MFMA16(a, b, c) __builtin_amdgcn_mfma_f32_16x16x32_bf16((a), (b), (c), 0, 0, 0)

// ---------------------------------------------------------------------------
// weight fp32 -> bf16 conversion (runs every launch; d_ws is re-poisoned)
// ---------------------------------------------------------------------------
__global__ void cvt_f32_bf16(const float* __restrict__ src, bf16* __restrict__ dst, int n) {
    int i = (blockIdx.x * 256 + threadIdx.x) * 4;
    if (i < n) {
        float4 v = *(const float4*)(src + i);
        bf16x4 o = {(bf16)v.x, (bf16)v.y, (bf16)v.z, (bf16)v.w};
        *(bf16x4*)(dst + i) = o;
    }
}

// ---------------------------------------------------------------------------
// helpers
// ---------------------------------------------------------------------------
__device__ __forceinline__ float allsum64(float v) {
#pragma unroll
    for (int m = 1; m < 64; m <<= 1) v += __shfl_xor(v, m, 64);
    return v;
}

// LayerNorm of one 128-elem bf16 row in LDS; one wave per row; lane handles d=lane, d+64
__device__ __forceinline__ void ln_bf16_row(bf16* row, const float* g, const float* b,
                                            const float* add, int lane) {
    float v0 = (float)row[lane], v1 = (float)row[lane + 64];
    float mu = allsum64(v0 + v1) * (1.0f / 128.0f);
    float c0 = v0 - mu, c1 = v1 - mu;
    float var = allsum64(c0 * c0 + c1 * c1) * (1.0f / 128.0f);
    float rs = rsqrtf(var + 1e-5f);
    float o0 = c0 * rs * g[lane] + b[lane];
    float o1 = c1 * rs * g[lane + 64] + b[lane + 64];
    if (add) { o0 += add[lane]; o1 += add[lane + 64]; }
    row[lane] = (bf16)o0;
    row[lane + 64] = (bf16)o1;
}

__device__ __forceinline__ void ln_f32_row(float* row, const float* g, const float* b, int lane) {
    float v0 = row[lane], v1 = row[lane + 64];
    float mu = allsum64(v0 + v1) * (1.0f / 128.0f);
    float c0 = v0 - mu, c1 = v1 - mu;
    float var = allsum64(c0 * c0 + c1 * c1) * (1.0f / 128.0f);
    float rs = rsqrtf(var + 1e-5f);
    row[lane] = c0 * rs * g[lane] + b[lane];
    row[lane + 64] = c1 * rs * g[lane + 64] + b[lane + 64];
}

// stage a 128-col x 128-k bf16 weight slice (rows = out-cols, row stride sstride) into sW[128][136]
__device__ __forceinline__ void stage_w128(const bf16* __restrict__ src, int sstride,
                                           bf16* __restrict__ dst, int t) {
#pragma unroll
    for (int i = 0; i < 8; ++i) {
        int lin = t + i * 256;           // 2048 x 16B chunks
        int c = lin >> 4;
        int k8 = (lin & 15) * 8;
        *(uint4*)(dst + c * 136 + k8) = *(const uint4*)(src + c * sstride + k8);
    }
}

// stage 32 rows x 128 k of fp32 global x into bf16 LDS [32][136]
__device__ __forceinline__ void stage_x128(const float* __restrict__ src, long sstride, long kofs,
                                           bf16* __restrict__ dst, int t, int rowbase) {
#pragma unroll
    for (int i = 0; i < 4; ++i) {
        int lin = t + i * 256;           // 1024 float4s
        int r = lin >> 5;
        int f4 = (lin & 31) * 4;
        const float* p = src + (long)(rowbase + r) * sstride + kofs + f4;
        float4 v = *(const float4*)p;
        bf16x4 o = {(bf16)v.x, (bf16)v.y, (bf16)v.z, (bf16)v.w};
        *(bf16x4*)(dst + r * 136 + f4) = o;
    }
}

// 32(M) x 128(N) x 128(K) MFMA tile: wave wid owns cols [wid*32, wid*32+32)
// A: bf16 LDS rows (row stride astride), W: staged sW[128][136]
__device__ __forceinline__ void gemm_k128(const bf16* __restrict__ A, int astride,
                                          const bf16* __restrict__ W,
                                          int lane, int wid, f32x4 acc[2][2]) {
    const int m = lane & 15;
    const int kq = (lane >> 4) * 8;
    const bf16* a0p = A + m * astride + kq;
    const bf16* a1p = a0p + 16 * astride;
    const bf16* b0p = W + (wid * 32 + m) * 136 + kq;
    const bf16* b1p = b0p + 16 * 136;
#pragma unroll
    for (int kc = 0; kc < 4; ++kc) {
        int k = kc * 32;
        bf16x8 a0 = *(const bf16x8*)(a0p + k);
        bf16x8 a1 = *(const bf16x8*)(a1p + k);
        bf16x8 b0 = *(const bf16x8*)(b0p + k);
        bf16x8 b1 = *(const bf16x8*)(b1p + k);
        acc[0][0] = MFMA16(a0, b0, acc[0][0]);
        acc[0][1] = MFMA16(a0, b1, acc[0][1]);
        acc[1][0] = MFMA16(a1, b0, acc[1][0]);
        acc[1][1] = MFMA16(a1, b1, acc[1][1]);
    }
}

// iterate D-layout elements: row = mt*16 + (lane>>4)*4 + j, col = wid*32 + nt*16 + (lane&15)
template <typename F>
__device__ __forceinline__ void foreach_acc(const f32x4 (&acc)[2][2], int lane, int wid, F&& f) {
    const int rlo = (lane >> 4) * 4;
    const int cl = lane & 15;
#pragma unroll
    for (int mt = 0; mt < 2; ++mt)
#pragma unroll
        for (int nt = 0; nt < 2; ++nt)
#pragma unroll
            for (int j = 0; j < 4; ++j)
                f(mt * 16 + rlo + j, wid * 32 + nt * 16 + cl, acc[mt][nt][j]);
}

#define ZACC()                                    \
    do {                                          \
        acc[0][0] = zz; acc[0][1] = zz;           \
        acc[1][0] = zz; acc[1][1] = zz;           \
    } while (0)

// ---------------------------------------------------------------------------
// fused kernel: 32 rows per workgroup, 256 threads (4 waves)
// ---------------------------------------------------------------------------
__global__ __launch_bounds__(256) void cmaf_kernel(
    const float* __restrict__ xs, const float* __restrict__ xg, const float* __restrict__ xf,
    const bf16* __restrict__ wsp, const bf16* __restrict__ wgf, const bf16* __restrict__ wqkv,
    const bf16* __restrict__ wout, const bf16* __restrict__ w1, const bf16* __restrict__ w2,
    const float* __restrict__ projb, const float* __restrict__ pg_, const float* __restrict__ pb_,
    const float* __restrict__ memb, const float* __restrict__ inb,
    const float* __restrict__ outb, const float* __restrict__ ag_, const float* __restrict__ ab_,
    const float* __restrict__ fb1, const float* __restrict__ fb2,
    const float* __restrict__ fg_, const float* __restrict__ fbb_,
    const float* __restrict__ gw, const float* __restrict__ gb,
    float* __restrict__ out) {
    const int t = threadIdx.x;
    const int lane = t & 63;
    const int wid = t >> 6;
    const int rowbase = blockIdx.x * 32;

    // LDS: 26112 + 26112 + 52224 + 16896 + 34816 + 512 = 156,672 B (<= 160 KiB)
    __shared__ __align__(16) bf16 sP[32 * 3 * 136];
    __shared__ __align__(16) bf16 sX1[32 * 3 * 136];
    __shared__ __align__(16) unsigned char sU[52224];  // QKV+O | X2(fp32) | x-staging
    __shared__ __align__(16) bf16 sH[32 * 264];
    __shared__ __align__(16) bf16 sW[128 * 136];
    __shared__ float sGl[32 * 4];

    bf16* sQKV = (bf16*)sU;               // [32][5][136]  z: 0=q 1=k0 2=k1 3=v0 4=v1
    bf16* sO = (bf16*)(sU + 43520);       // [32][136]
    bf16* sXb = (bf16*)sU;                // [32][136] staging (phase A only)
    float* sX2 = (float*)sU;              // [32][3][132] fp32 (FFN phase onward)

    f32x4 acc[2][2];
    const f32x4 zz = {0.f, 0.f, 0.f, 0.f};

    // ============ Phase A: P_pre = projections ============
    // n = 0: spatial, K = 1280
    ZACC();
    for (int sc = 0; sc < 10; ++sc) {
        __syncthreads();
        stage_x128(xs, 1280, sc * 128, sXb, t, rowbase);
        stage_w128(wsp + sc * 128, 1280, sW, t);
        __syncthreads();
        gemm_k128(sXb, 136, sW, lane, wid, acc);
    }
    foreach_acc(acc, lane, wid, [&](int row, int col, float v) {
        sP[(row * 3 + 0) * 136 + col] = (bf16)(v + projb[col]);
    });
    // n = 1 (gradient), n = 2 (frequency), K = 128
    for (int g2 = 0; g2 < 2; ++g2) {
        const float* xsrc = g2 ? xf : xg;
        __syncthreads();
        stage_x128(xsrc, 128, 0, sXb, t, rowbase);
        stage_w128(wgf + g2 * 16384, 128, sW, t);
        __syncthreads();
        ZACC();
        gemm_k128(sXb, 136, sW, lane, wid, acc);
        foreach_acc(acc, lane, wid, [&](int row, int col, float v) {
            sP[(row * 3 + 1 + g2) * 136 + col] = (bf16)(v + projb[(1 + g2) * 128 + col]);
        });
    }
    __syncthreads();
    // LN(P) * g + b + mod_emb   (96 rows: wave per (r,n))
    for (int p = wid; p < 96; p += 4) {
        int r = p & 31, n = p >> 5;
        ln_bf16_row(sP + (r * 3 + n) * 136, pg_ + n * 128, pb_ + n * 128, memb + n * 128, lane);
    }

    // ============ Attention per stream n ============
    for (int n = 0; n < 3; ++n) {
        const int m0 = (n == 0) ? 1 : 0;
        const int m1 = (n == 2) ? 1 : 2;
        // q
        __syncthreads();
        stage_w128(wqkv + (n * 384 + 0) * 128, 128, sW, t);
        __syncthreads();
        ZACC();
        gemm_k128(sP + n * 136, 408, sW, lane, wid, acc);
        foreach_acc(acc, lane, wid, [&](int row, int col, float v) {
            sQKV[(row * 5 + 0) * 136 + col] = (bf16)(v + inb[n * 384 + col]);
        });
        // k (two kv sources, same weights)
        __syncthreads();
        stage_w128(wqkv + (n * 384 + 128) * 128, 128, sW, t);
        __syncthreads();
        ZACC();
        gemm_k128(sP + m0 * 136, 408, sW, lane, wid, acc);
        foreach_acc(acc, lane, wid, [&](int row, int col, float v) {
            sQKV[(row * 5 + 1) * 136 + col] = (bf16)(v + inb[n * 384 + 128 + col]);
        });
        ZACC();
        gemm_k128(sP + m1 * 136, 408, sW, lane, wid, acc);
        foreach_acc(acc, lane, wid, [&](int row, int col, float v) {
            sQKV[(row * 5 + 2) * 136 + col] = (bf16)(v + inb[n * 384 + 128 + col]);
        });
        // v
        __syncthreads();
        stage_w128(wqkv + (n * 384 + 256) * 128, 128, sW, t);
        __syncthreads();
        ZACC();
        gemm_k128(sP + m0 * 136, 408, sW, lane, wid, acc);
        foreach_acc(acc, lane, wid, [&](int row, int col, float v) {
            sQKV[(row * 5 + 3) * 136 + col] = (bf16)(v + inb[n * 384 + 256 + col]);
        });
        ZACC();
        gemm_k128(sP + m1 * 136, 408, sW, lane, wid, acc);
        foreach_acc(acc, lane, wid, [&](int row, int col, float v) {
            sQKV[(row * 5 + 4) * 136 + col] = (bf16)(v + inb[n * 384 + 256 + col]);
        });
        __syncthreads();
        // softmax over 2 kv slots, per (row, head)
        if (t < 128) {
            int r = t >> 2, h = t & 3;
            const bf16* base = sQKV + r * 5 * 136 + h * 32;
            const bf16* qp = base;
            const bf16* k0p = base + 136;
            const bf16* k1p = base + 2 * 136;
            const bf16* v0p = base + 3 * 136;
            const bf16* v1p = base + 4 * 136;
            float d0 = 0.f, d1 = 0.f;
#pragma unroll 8
            for (int i = 0; i < 32; ++i) {
                float q = (float)qp[i];
                d0 += q * (float)k0p[i];
                d1 += q * (float)k1p[i];
            }
            const float scl = 0.17677669529663687f;  // 1/sqrt(32)
            d0 *= scl; d1 *= scl;
            float mx = fmaxf(d0, d1);
            float e0 = expf(d0 - mx), e1 = expf(d1 - mx);
            float inv = 1.f / (e0 + e1);
            float a0 = e0 * inv, a1 = e1 * inv;
            bf16* op = sO + r * 136 + h * 32;
#pragma unroll 8
            for (int i = 0; i < 32; ++i)
                op[i] = (bf16)(a0 * (float)v0p[i] + a1 * (float)v1p[i]);
        }
        __syncthreads();
        // out-proj + residual P  -> x1 (pre-LN)
        stage_w128(wout + n * 16384, 128, sW, t);
        __syncthreads();
        ZACC();
        gemm_k128(sO, 136, sW, lane, wid, acc);
        foreach_acc(acc, lane, wid, [&](int row, int col, float v) {
            float val = v + outb[n * 128 + col] + (float)sP[(row * 3 + n) * 136 + col];
            sX1[(row * 3 + n) * 136 + col] = (bf16)val;
        });
        __syncthreads();
        for (int p = wid; p < 32; p += 4)
            ln_bf16_row(sX1 + (p * 3 + n) * 136, ag_ + n * 128, ab_ + n * 128, nullptr, lane);
    }

    // ============ FFN per stream n ============
    for (int n = 0; n < 3; ++n) {
        for (int half = 0; half < 2; ++half) {
            __syncthreads();
            stage_w128(w1 + (n * 256 + half * 128) * 128, 128, sW, t);
            __syncthreads();
            ZACC();
            gemm_k128(sX1 + n * 136, 408, sW, lane, wid, acc);
            foreach_acc(acc, lane, wid, [&](int row, int col, float v) {
                float x = v + fb1[n * 256 + half * 128 + col];
                float ge = 0.5f * x * (1.0f + erff(x * 0.70710678118654752f));
                sH[row * 264 + half * 128 + col] = (bf16)ge;
            });
        }
        ZACC();
        for (int ksc = 0; ksc < 2; ++ksc) {
            __syncthreads();
            stage_w128(w2 + n * 32768 + ksc * 128, 256, sW, t);
            __syncthreads();
            gemm_k128(sH + ksc * 128, 264, sW, lane, wid, acc);
        }
        foreach_acc(acc, lane, wid, [&](int row, int col, float v) {
            float val = v + fb2[n * 128 + col] + (float)sX1[(row * 3 + n) * 136 + col];
            sX2[(row * 3 + n) * 132 + col] = val;   // fp32, pre-LN
        });
    }
    __syncthreads();
    for (int p = wid; p < 96; p += 4) {
        int r = p & 31, n = p >> 5;
        ln_f32_row(sX2 + (r * 3 + n) * 132, fg_ + n * 128, fbb_ + n * 128, lane);
    }
    __syncthreads();

    // ============ Gates + fused output ============
    if (t < 96) {
        int r = t / 3, j = t % 3;
        float a = gb[j];
        const float* gwj = gw + j * 384;
        for (int nn = 0; nn < 3; ++nn) {
            const float* xr = sX2 + (r * 3 + nn) * 132;
            const float* gp = gwj + nn * 128;
#pragma unroll 4
            for (int d = 0; d < 128; ++d) a += xr[d] * gp[d];
        }
        sGl[r * 4 + j] = a;
    }
    __syncthreads();
    if (t < 32) {
        float l0 = sGl[t * 4], l1 = sGl[t * 4 + 1], l2 = sGl[t * 4 + 2];
        float mx = fmaxf(l0, fmaxf(l1, l2));
        float e0 = expf(l0 - mx), e1 = expf(l1 - mx), e2 = expf(l2 - mx);
        float inv = 1.f / (e0 + e1 + e2);
        sGl[t * 4] = e0 * inv;
        sGl[t * 4 + 1] = e1 * inv;
        sGl[t * 4 + 2] = e2 * inv;
    }
    __syncthreads();
    {
        int c = t & 127, rh = t >> 7;
#pragma unroll
        for (int rr = 0; rr < 16; ++rr) {
            int r = rh * 16 + rr;
            float v = sX2[(r * 3 + 0) * 132 + c] * sGl[r * 4 + 0] +
                      sX2[(r * 3 + 1) * 132 + c] * sGl[r * 4 + 1] +
                      sX2[(r * 3 + 2) * 132 + c] * sGl[r * 4 + 2];
            out[(long)(rowbase + r) * 128 + c] = v;
        }
    }
}

// ---------------------------------------------------------------------------
extern "C" void kernel_launch(void* const* d_in, const int* in_sizes, int n_in,
                              void* d_out, int out_size, void* d_ws, size_t ws_size,
                              hipStream_t stream) {
    const float* xs = (const float*)d_in[0];
    const float* xg = (const float*)d_in[1];
    const float* xf = (const float*)d_in[2];
    const float* w_sp = (const float*)d_in[3];
    const float* w_gf = (const float*)d_in[4];
    const float* proj_b = (const float*)d_in[5];
    const float* proj_g = (const float*)d_in[6];
    const float* proj_bb = (const float*)d_in[7];
    const float* mod_emb = (const float*)d_in[8];
    const float* in_w = (const float*)d_in[9];
    const float* in_b = (const float*)d_in[10];
    const float* out_w = (const float*)d_in[11];
    const float* out_b = (const float*)d_in[12];
    const float* attn_g = (const float*)d_in[13];
    const float* attn_b = (const float*)d_in[14];
    const float* ffn_w1 = (const float*)d_in[15];
    const float* ffn_b1 = (const float*)d_in[16];
    const float* ffn_w2 = (const float*)d_in[17];
    const float* ffn_b2 = (const float*)d_in[18];
    const float* ffn_g = (const float*)d_in[19];
    const float* ffn_bb = (const float*)d_in[20];
    const float* gate_w = (const float*)d_in[21];
    const float* gate_b = (const float*)d_in[22];

    bf16* wb = (bf16*)d_ws;          // 1,179,648 B of bf16 weights
    bf16* wsp = wb;                  // 163840
    bf16* wgf = wb + 163840;         // 32768
    bf16* wqkv = wb + 196608;        // 147456
    bf16* wout = wb + 344064;        // 49152
    bf16* w1 = wb + 393216;          // 98304
    bf16* w2 = wb + 491520;          // 98304

    cvt_f32_bf16<<<160, 256, 0, stream>>>(w_sp, wsp, 163840);
    cvt_f32_bf16<<<32, 256, 0, stream>>>(w_gf, wgf, 32768);
    cvt_f32_bf16<<<144, 256, 0, stream>>>(in_w, wqkv, 147456);
    cvt_f32_bf16<<<48, 256, 0, stream>>>(out_w, wout, 49152);
    cvt_f32_bf16<<<96, 256, 0, stream>>>(ffn_w1, w1, 98304);
    cvt_f32_bf16<<<96, 256, 0, stream>>>(ffn_w2, w2, 98304);

    int B = in_sizes[1] / 128;
    cmaf_kernel<<<B / 32, 256, 0, stream>>>(
        xs, xg, xf, wsp, wgf, wqkv, wout, w1, w2,
        proj_b, proj_g, proj_bb, mod_emb, in_b, out_b, attn_g, attn_b,
        ffn_b1, ffn_b2, ffn_g, ffn_bb, gate_w, gate_b, (float*)d_out);
}

// Round 2
// 940.832 us; speedup vs baseline: 1.4074x; 1.4074x over previous
//
#include <hip/hip_runtime.h>

typedef __bf16 bf16;
typedef __bf16 bf16x8 __attribute__((ext_vector_type(8)));
typedef __bf16 bf16x4 __attribute__((ext_vector_type(4)));
typedef __bf16 bf16x2 __attribute__((ext_vector_type(2)));
typedef float f32x4 __attribute__((ext_vector_type(4)));

#define MFMA16(a, b, c) __builtin_amdgcn_mfma_f32_16x16x32_bf16((a), (b), (c), 0, 0, 0)

// ---------------------------------------------------------------------------
// fused weight fp32 -> bf16 conversion. dst regions are contiguous in ws, so
// dst index == 4*global chunk id. 147456 float4 chunks total = 576 blocks.
// ---------------------------------------------------------------------------
__global__ __launch_bounds__(256) void cvt_all(
    const float* __restrict__ s0, const float* __restrict__ s1, const float* __restrict__ s2,
    const float* __restrict__ s3, const float* __restrict__ s4, const float* __restrict__ s5,
    bf16* __restrict__ dst) {
    int g = blockIdx.x * 256 + threadIdx.x;
    const float* src;
    int local;
    if (g < 40960)       { src = s0; local = g; }
    else if (g < 49152)  { src = s1; local = g - 40960; }
    else if (g < 86016)  { src = s2; local = g - 49152; }
    else if (g < 98304)  { src = s3; local = g - 86016; }
    else if (g < 122880) { src = s4; local = g - 98304; }
    else                 { src = s5; local = g - 122880; }
    float4 v = *(const float4*)(src + (long)local * 4);
    bf16x4 o = {(bf16)v.x, (bf16)v.y, (bf16)v.z, (bf16)v.w};
    *(bf16x4*)(dst + (long)g * 4) = o;
}

// ---------------------------------------------------------------------------
// helpers
// ---------------------------------------------------------------------------
__device__ __forceinline__ float allsum64(float v) {
#pragma unroll
    for (int m = 1; m < 64; m <<= 1) v += __shfl_xor(v, m, 64);
    return v;
}

// LayerNorm of one 128-elem bf16 row in LDS; one wave per row
__device__ __forceinline__ void ln_bf16_row(bf16* row, const float* g, const float* b,
                                            const float* add, int lane) {
    float v0 = (float)row[lane], v1 = (float)row[lane + 64];
    float mu = allsum64(v0 + v1) * (1.0f / 128.0f);
    float c0 = v0 - mu, c1 = v1 - mu;
    float var = allsum64(c0 * c0 + c1 * c1) * (1.0f / 128.0f);
    float rs = rsqrtf(var + 1e-5f);
    float o0 = c0 * rs * g[lane] + b[lane];
    float o1 = c1 * rs * g[lane + 64] + b[lane + 64];
    if (add) { o0 += add[lane]; o1 += add[lane + 64]; }
    row[lane] = (bf16)o0;
    row[lane + 64] = (bf16)o1;
}

__device__ __forceinline__ void ln_f32_row(float* row, const float* g, const float* b, int lane) {
    float v0 = row[lane], v1 = row[lane + 64];
    float mu = allsum64(v0 + v1) * (1.0f / 128.0f);
    float c0 = v0 - mu, c1 = v1 - mu;
    float var = allsum64(c0 * c0 + c1 * c1) * (1.0f / 128.0f);
    float rs = rsqrtf(var + 1e-5f);
    row[lane] = c0 * rs * g[lane] + b[lane];
    row[lane + 64] = c1 * rs * g[lane + 64] + b[lane + 64];
}

// stage a 128-col x 128-k bf16 weight slice (row stride sstride) into sW[128][136]
__device__ __forceinline__ void stage_w128(const bf16* __restrict__ src, int sstride,
                                           bf16* __restrict__ dst, int t) {
#pragma unroll
    for (int i = 0; i < 8; ++i) {
        int lin = t + i * 256;           // 2048 x 16B chunks
        int c = lin >> 4;
        int k8 = (lin & 15) * 8;
        *(uint4*)(dst + c * 136 + k8) = *(const uint4*)(src + (long)c * sstride + k8);
    }
}

// stage 32 rows x 128 k of fp32 global x into bf16 LDS [32][136]
__device__ __forceinline__ void stage_x128(const float* __restrict__ src, long sstride, long kofs,
                                           bf16* __restrict__ dst, int t, long rowbase) {
#pragma unroll
    for (int i = 0; i < 4; ++i) {
        int lin = t + i * 256;           // 1024 float4s
        int r = lin >> 5;
        int f4 = (lin & 31) * 4;
        const float* p = src + (rowbase + r) * sstride + kofs + f4;
        float4 v = *(const float4*)p;
        bf16x4 o = {(bf16)v.x, (bf16)v.y, (bf16)v.z, (bf16)v.w};
        *(bf16x4*)(dst + r * 136 + f4) = o;
    }
}

// 32(M) x 128(N) x 128(K) MFMA tile: wave wid owns cols [wid*32, wid*32+32)
__device__ __forceinline__ void gemm_k128(const bf16* __restrict__ A, int astride,
                                          const bf16* __restrict__ W,
                                          int lane, int wid, f32x4 acc[2][2]) {
    const int m = lane & 15;
    const int kq = (lane >> 4) * 8;
    const bf16* a0p = A + m * astride + kq;
    const bf16* a1p = a0p + 16 * astride;
    const bf16* b0p = W + (wid * 32 + m) * 136 + kq;
    const bf16* b1p = b0p + 16 * 136;
#pragma unroll
    for (int kc = 0; kc < 4; ++kc) {
        int k = kc * 32;
        bf16x8 a0 = *(const bf16x8*)(a0p + k);
        bf16x8 a1 = *(const bf16x8*)(a1p + k);
        bf16x8 b0 = *(const bf16x8*)(b0p + k);
        bf16x8 b1 = *(const bf16x8*)(b1p + k);
        acc[0][0] = MFMA16(a0, b0, acc[0][0]);
        acc[0][1] = MFMA16(a0, b1, acc[0][1]);
        acc[1][0] = MFMA16(a1, b0, acc[1][0]);
        acc[1][1] = MFMA16(a1, b1, acc[1][1]);
    }
}

template <typename F>
__device__ __forceinline__ void foreach_acc(const f32x4 (&acc)[2][2], int lane, int wid, F&& f) {
    const int rlo = (lane >> 4) * 4;
    const int cl = lane & 15;
#pragma unroll
    for (int mt = 0; mt < 2; ++mt)
#pragma unroll
        for (int nt = 0; nt < 2; ++nt)
#pragma unroll
            for (int j = 0; j < 4; ++j)
                f(mt * 16 + rlo + j, wid * 32 + nt * 16 + cl, acc[mt][nt][j]);
}

__device__ __forceinline__ void zacc(f32x4 (&a)[2][2]) {
    const f32x4 z = {0.f, 0.f, 0.f, 0.f};
    a[0][0] = z; a[0][1] = z; a[1][0] = z; a[1][1] = z;
}

// add per-col bias to acc: cols wid*32+cl (nt=0) and +16 (nt=1)
__device__ __forceinline__ void add_bias(f32x4 (&a)[2][2], const float* __restrict__ b,
                                         int lane, int wid) {
    float b0 = b[wid * 32 + (lane & 15)];
    float b1 = b[wid * 32 + (lane & 15) + 16];
#pragma unroll
    for (int mt = 0; mt < 2; ++mt)
#pragma unroll
        for (int j = 0; j < 4; ++j) { a[mt][0][j] += b0; a[mt][1][j] += b1; }
}

// ---------------------------------------------------------------------------
// Kernel A: projections -> P (post-LN + mod_emb), bf16 [B][3][128]
// LDS: 34816 + 8704 + 26112 = 69632 B -> 2 WG/CU
// ---------------------------------------------------------------------------
__global__ __launch_bounds__(256, 2) void proj_kernel(
    const float* __restrict__ xs, const float* __restrict__ xg, const float* __restrict__ xf,
    const bf16* __restrict__ wsp, const bf16* __restrict__ wgf,
    const float* __restrict__ projb, const float* __restrict__ pg_, const float* __restrict__ pb_,
    const float* __restrict__ memb, bf16* __restrict__ Pg) {
    const int t = threadIdx.x, lane = t & 63, wid = t >> 6;
    const long rowbase = (long)blockIdx.x * 32;
    __shared__ __align__(16) bf16 sW[128 * 136];
    __shared__ __align__(16) bf16 sXb[32 * 136];
    __shared__ __align__(16) bf16 sP[32 * 3 * 136];

    f32x4 acc[2][2];
    zacc(acc);
    for (int sc = 0; sc < 10; ++sc) {
        __syncthreads();
        stage_x128(xs, 1280, sc * 128, sXb, t, rowbase);
        stage_w128(wsp + sc * 128, 1280, sW, t);
        __syncthreads();
        gemm_k128(sXb, 136, sW, lane, wid, acc);
    }
    foreach_acc(acc, lane, wid, [&](int row, int col, float v) {
        sP[(row * 3 + 0) * 136 + col] = (bf16)(v + projb[col]);
    });
    for (int g2 = 0; g2 < 2; ++g2) {
        __syncthreads();
        stage_x128(g2 ? xf : xg, 128, 0, sXb, t, rowbase);
        stage_w128(wgf + g2 * 16384, 128, sW, t);
        __syncthreads();
        zacc(acc);
        gemm_k128(sXb, 136, sW, lane, wid, acc);
        foreach_acc(acc, lane, wid, [&](int row, int col, float v) {
            sP[(row * 3 + 1 + g2) * 136 + col] = (bf16)(v + projb[(1 + g2) * 128 + col]);
        });
    }
    __syncthreads();
    for (int p = wid; p < 96; p += 4) {
        int r = p & 31, n = p >> 5;
        ln_bf16_row(sP + (r * 3 + n) * 136, pg_ + n * 128, pb_ + n * 128, memb + n * 128, lane);
    }
    __syncthreads();
    // write 32x384 bf16, coalesced uint4: global offset = rowbase*384 + lin*8
#pragma unroll
    for (int i = 0; i < 6; ++i) {
        int lin = t + i * 256;           // 0..1535
        int r = lin / 48, cr = lin % 48;
        int s = cr >> 4, c8 = (cr & 15) * 8;
        *(uint4*)(Pg + rowbase * 384 + (long)lin * 8) =
            *(const uint4*)(sP + (r * 3 + s) * 136 + c8);
    }
}

// ---------------------------------------------------------------------------
// Kernel B: attention per stream -> x1 (post-LN), bf16 [B][3][128]
// q/k/v live in MFMA accumulators (wave w == head w); only o round-trips LDS.
// LDS: 26112 + 34816 + 8704 + 8704 = 78336 B -> 2 WG/CU
// ---------------------------------------------------------------------------
__global__ __launch_bounds__(256, 2) void attn_kernel(
    const bf16* __restrict__ Pg, const bf16* __restrict__ wqkv, const bf16* __restrict__ wout,
    const float* __restrict__ inb, const float* __restrict__ outb,
    const float* __restrict__ ag_, const float* __restrict__ ab_,
    bf16* __restrict__ X1g) {
    const int t = threadIdx.x, lane = t & 63, wid = t >> 6;
    const int n = blockIdx.y;
    const long rowbase = (long)blockIdx.x * 32;
    const int m0 = (n == 0) ? 1 : 0;
    const int m1 = (n == 2) ? 1 : 2;
    __shared__ __align__(16) bf16 sP[32 * 3 * 136];
    __shared__ __align__(16) bf16 sW[128 * 136];
    __shared__ __align__(16) bf16 sO[32 * 136];
    __shared__ __align__(16) bf16 sX1[32 * 136];

    // load P tile (all 3 streams) + stage Wq
#pragma unroll
    for (int i = 0; i < 6; ++i) {
        int lin = t + i * 256;
        int r = lin / 48, cr = lin % 48;
        int s = cr >> 4, c8 = (cr & 15) * 8;
        *(uint4*)(sP + (r * 3 + s) * 136 + c8) =
            *(const uint4*)(Pg + rowbase * 384 + (long)lin * 8);
    }
    stage_w128(wqkv + (long)(n * 384) * 128, 128, sW, t);
    __syncthreads();

    f32x4 aq[2][2], ak0[2][2], ak1[2][2];
    zacc(aq);
    gemm_k128(sP + n * 136, 408, sW, lane, wid, aq);
    add_bias(aq, inb + n * 384, lane, wid);
    __syncthreads();
    stage_w128(wqkv + (long)(n * 384 + 128) * 128, 128, sW, t);
    __syncthreads();
    zacc(ak0); zacc(ak1);
    gemm_k128(sP + m0 * 136, 408, sW, lane, wid, ak0);
    gemm_k128(sP + m1 * 136, 408, sW, lane, wid, ak1);
    add_bias(ak0, inb + n * 384 + 128, lane, wid);
    add_bias(ak1, inb + n * 384 + 128, lane, wid);

    // scores + softmax: head = wid; reduce over 16 lanes of the quad
    float a0_[2][4], a1_[2][4];
    const float scl = 0.17677669529663687f;  // 1/sqrt(32)
#pragma unroll
    for (int mt = 0; mt < 2; ++mt)
#pragma unroll
        for (int j = 0; j < 4; ++j) {
            float d0 = aq[mt][0][j] * ak0[mt][0][j] + aq[mt][1][j] * ak0[mt][1][j];
            float d1 = aq[mt][0][j] * ak1[mt][0][j] + aq[mt][1][j] * ak1[mt][1][j];
#pragma unroll
            for (int m = 1; m < 16; m <<= 1) {
                d0 += __shfl_xor(d0, m, 64);
                d1 += __shfl_xor(d1, m, 64);
            }
            d0 *= scl; d1 *= scl;
            float mx = fmaxf(d0, d1);
            float e0 = expf(d0 - mx), e1 = expf(d1 - mx);
            float inv = 1.f / (e0 + e1);
            a0_[mt][j] = e0 * inv;
            a1_[mt][j] = e1 * inv;
        }

    __syncthreads();
    stage_w128(wqkv + (long)(n * 384 + 256) * 128, 128, sW, t);
    __syncthreads();
    f32x4 av0[2][2], av1[2][2];
    zacc(av0); zacc(av1);
    gemm_k128(sP + m0 * 136, 408, sW, lane, wid, av0);
    gemm_k128(sP + m1 * 136, 408, sW, lane, wid, av1);
    add_bias(av0, inb + n * 384 + 256, lane, wid);
    add_bias(av1, inb + n * 384 + 256, lane, wid);
    {
        const int rlo = (lane >> 4) * 4, cl = lane & 15;
#pragma unroll
        for (int mt = 0; mt < 2; ++mt)
#pragma unroll
            for (int nt = 0; nt < 2; ++nt)
#pragma unroll
                for (int j = 0; j < 4; ++j) {
                    float o = a0_[mt][j] * av0[mt][nt][j] + a1_[mt][j] * av1[mt][nt][j];
                    sO[(mt * 16 + rlo + j) * 136 + wid * 32 + nt * 16 + cl] = (bf16)o;
                }
    }
    __syncthreads();
    stage_w128(wout + (long)n * 16384, 128, sW, t);
    __syncthreads();
    f32x4 acc[2][2];
    zacc(acc);
    gemm_k128(sO, 136, sW, lane, wid, acc);
    foreach_acc(acc, lane, wid, [&](int row, int col, float v) {
        float val = v + outb[n * 128 + col] + (float)sP[(row * 3 + n) * 136 + col];
        sX1[row * 136 + col] = (bf16)val;
    });
    __syncthreads();
    for (int p = wid; p < 32; p += 4)
        ln_bf16_row(sX1 + p * 136, ag_ + n * 128, ab_ + n * 128, nullptr, lane);
    __syncthreads();
#pragma unroll
    for (int i = 0; i < 2; ++i) {
        int lin = t + i * 256;           // 0..511
        int r = lin >> 4, c8 = (lin & 15) * 8;
        *(uint4*)(X1g + (rowbase + r) * 384 + n * 128 + c8) =
            *(const uint4*)(sX1 + r * 136 + c8);
    }
}

// ---------------------------------------------------------------------------
// Kernel C: FFN per stream -> x2 (post-LN), bf16 [B][3][128]
// LDS: 8704 + 34816 + 16896 + 16896 = 77312 B -> 2 WG/CU
// ---------------------------------------------------------------------------
__global__ __launch_bounds__(256, 2) void ffn_kernel(
    const bf16* __restrict__ X1g, const bf16* __restrict__ w1, const bf16* __restrict__ w2,
    const float* __restrict__ fb1, const float* __restrict__ fb2,
    const float* __restrict__ fg_, const float* __restrict__ fbb_,
    bf16* __restrict__ X2g) {
    const int t = threadIdx.x, lane = t & 63, wid = t >> 6;
    const int n = blockIdx.y;
    const long rowbase = (long)blockIdx.x * 32;
    __shared__ __align__(16) bf16 sX1[32 * 136];
    __shared__ __align__(16) bf16 sW[128 * 136];
    __shared__ __align__(16) bf16 sH[32 * 264];
    __shared__ __align__(16) float sX2[32 * 132];

    // load x1 slice + stage w1 half0
#pragma unroll
    for (int i = 0; i < 2; ++i) {
        int lin = t + i * 256;
        int r = lin >> 4, c8 = (lin & 15) * 8;
        *(uint4*)(sX1 + r * 136 + c8) =
            *(const uint4*)(X1g + (rowbase + r) * 384 + n * 128 + c8);
    }
    stage_w128(w1 + (long)(n * 256) * 128, 128, sW, t);
    __syncthreads();

    f32x4 acc[2][2];
    for (int half = 0; half < 2; ++half) {
        if (half) {
            __syncthreads();
            stage_w128(w1 + (long)(n * 256 + 128) * 128, 128, sW, t);
            __syncthreads();
        }
        zacc(acc);
        gemm_k128(sX1, 136, sW, lane, wid, acc);
        foreach_acc(acc, lane, wid, [&](int row, int col, float v) {
            float x = v + fb1[n * 256 + half * 128 + col];
            float ge = 0.5f * x * (1.0f + erff(x * 0.70710678118654752f));
            sH[row * 264 + half * 128 + col] = (bf16)ge;
        });
    }
    zacc(acc);
    for (int ksc = 0; ksc < 2; ++ksc) {
        __syncthreads();
        stage_w128(w2 + (long)n * 32768 + ksc * 128, 256, sW, t);
        __syncthreads();
        gemm_k128(sH + ksc * 128, 264, sW, lane, wid, acc);
    }
    foreach_acc(acc, lane, wid, [&](int row, int col, float v) {
        sX2[row * 132 + col] = v + fb2[n * 128 + col] + (float)sX1[row * 136 + col];
    });
    __syncthreads();
    for (int p = wid; p < 32; p += 4)
        ln_f32_row(sX2 + p * 132, fg_ + n * 128, fbb_ + n * 128, lane);
    __syncthreads();
#pragma unroll
    for (int i = 0; i < 8; ++i) {
        int lin = t + i * 256;           // 0..2047 pairs
        int r = lin >> 6, c2 = (lin & 63) * 2;
        bf16x2 o = {(bf16)sX2[r * 132 + c2], (bf16)sX2[r * 132 + c2 + 1]};
        *(bf16x2*)(X2g + (rowbase + r) * 384 + n * 128 + c2) = o;
    }
}

// ---------------------------------------------------------------------------
// Kernel D: gates + fused output (memory-bound)
// ---------------------------------------------------------------------------
__global__ __launch_bounds__(256) void gate_kernel(
    const bf16* __restrict__ X2g, const float* __restrict__ gw, const float* __restrict__ gb,
    float* __restrict__ out) {
    const int t = threadIdx.x, lane = t & 63, wid = t >> 6;
    const long rowbase = (long)blockIdx.x * 32;
    __shared__ float sGw[1152];
    for (int i = t; i < 1152; i += 256) sGw[i] = gw[i];
    __syncthreads();
    for (int r = wid; r < 32; r += 4) {
        const bf16* xr = X2g + (rowbase + r) * 384;
        int e = lane * 6;
        float x[6];
#pragma unroll
        for (int i = 0; i < 6; ++i) x[i] = (float)xr[e + i];
        float l0 = 0.f, l1 = 0.f, l2 = 0.f;
#pragma unroll
        for (int i = 0; i < 6; ++i) {
            l0 += x[i] * sGw[e + i];
            l1 += x[i] * sGw[384 + e + i];
            l2 += x[i] * sGw[768 + e + i];
        }
        l0 = allsum64(l0) + gb[0];
        l1 = allsum64(l1) + gb[1];
        l2 = allsum64(l2) + gb[2];
        float mx = fmaxf(l0, fmaxf(l1, l2));
        float e0 = expf(l0 - mx), e1 = expf(l1 - mx), e2 = expf(l2 - mx);
        float inv = 1.f / (e0 + e1 + e2);
        float g0 = e0 * inv, g1 = e1 * inv, g2 = e2 * inv;
        float o0 = g0 * (float)xr[lane] + g1 * (float)xr[128 + lane] + g2 * (float)xr[256 + lane];
        float o1 = g0 * (float)xr[lane + 64] + g1 * (float)xr[128 + lane + 64] +
                   g2 * (float)xr[256 + lane + 64];
        out[(rowbase + r) * 128 + lane] = o0;
        out[(rowbase + r) * 128 + lane + 64] = o1;
    }
}

// ---------------------------------------------------------------------------
extern "C" void kernel_launch(void* const* d_in, const int* in_sizes, int n_in,
                              void* d_out, int out_size, void* d_ws, size_t ws_size,
                              hipStream_t stream) {
    const float* xs = (const float*)d_in[0];
    const float* xg = (const float*)d_in[1];
    const float* xf = (const float*)d_in[2];
    const float* w_sp = (const float*)d_in[3];
    const float* w_gf = (const float*)d_in[4];
    const float* proj_b = (const float*)d_in[5];
    const float* proj_g = (const float*)d_in[6];
    const float* proj_bb = (const float*)d_in[7];
    const float* mod_emb = (const float*)d_in[8];
    const float* in_w = (const float*)d_in[9];
    const float* in_b = (const float*)d_in[10];
    const float* out_w = (const float*)d_in[11];
    const float* out_b = (const float*)d_in[12];
    const float* attn_g = (const float*)d_in[13];
    const float* attn_b = (const float*)d_in[14];
    const float* ffn_w1 = (const float*)d_in[15];
    const float* ffn_b1 = (const float*)d_in[16];
    const float* ffn_w2 = (const float*)d_in[17];
    const float* ffn_b2 = (const float*)d_in[18];
    const float* ffn_g = (const float*)d_in[19];
    const float* ffn_bb = (const float*)d_in[20];
    const float* gate_w = (const float*)d_in[21];
    const float* gate_b = (const float*)d_in[22];

    const int B = in_sizes[1] / 128;  // 65536

    bf16* wb = (bf16*)d_ws;
    bf16* wsp = wb;                    // 163840 elems
    bf16* wgf = wb + 163840;           // 32768
    bf16* wqkv = wb + 196608;          // 147456
    bf16* wout = wb + 344064;          // 49152
    bf16* w1 = wb + 393216;            // 98304
    bf16* w2 = wb + 491520;            // 98304
    bf16* Pbuf = wb + 589824;          // B*384 elems (reused as x2)
    bf16* X1buf = Pbuf + (long)B * 384;
    bf16* X2buf = Pbuf;                // alias: P dead after attn

    cvt_all<<<576, 256, 0, stream>>>(w_sp, w_gf, in_w, out_w, ffn_w1, ffn_w2, wb);
    proj_kernel<<<B / 32, 256, 0, stream>>>(xs, xg, xf, wsp, wgf, proj_b, proj_g, proj_bb,
                                            mod_emb, Pbuf);
    attn_kernel<<<dim3(B / 32, 3), 256, 0, stream>>>(Pbuf, wqkv, wout, in_b, out_b,
                                                     attn_g, attn_b, X1buf);
    ffn_kernel<<<dim3(B / 32, 3), 256, 0, stream>>>(X1buf, w1, w2, ffn_b1, ffn_b2,
                                                    ffn_g, ffn_bb, X2buf);
    gate_kernel<<<B / 32, 256, 0, stream>>>(X2buf, gate_w, gate_b, (float*)d_out);
}